// Round 1
// baseline (3073.202 us; speedup 1.0000x reference)
//
#include <hip/hip_runtime.h>

#define BATCH   16
#define NPTS    8192
#define NCH     64
#define NPOINT  1024
#define NSAMPLE 32
// f32(0.1**2) == 0.01f exactly (python double 0.010000000000000002 rounds to same f32)
#define R2 0.01f

// ---------------------------------------------------------------------------
// Kernel 1: furthest point sampling. One block (1024 threads) per batch.
// Bit-exact vs numpy: dist = ((dx*dx + dy*dy) + dz*dz) with _rn intrinsics
// (no FMA contraction), argmax with first-index tie-break.
// ---------------------------------------------------------------------------
__global__ __launch_bounds__(1024) void fps_kernel(const float* __restrict__ xyz,
                                                   float* __restrict__ new_xyz) {
    const int b = blockIdx.x;
    const int t = threadIdx.x;
    __shared__ float s_pts[NPTS * 3];   // 96 KB
    __shared__ float s_val[16];
    __shared__ int   s_idx[16];

    const float* g = xyz + (size_t)b * NPTS * 3;
    for (int i = t; i < NPTS * 3; i += 1024) s_pts[i] = g[i];
    __syncthreads();

    float px[8], py[8], pz[8], dist[8];
#pragma unroll
    for (int k = 0; k < 8; ++k) {
        const int p = t + k * 1024;
        px[k] = s_pts[3 * p + 0];
        py[k] = s_pts[3 * p + 1];
        pz[k] = s_pts[3 * p + 2];
        dist[k] = 1e10f;
    }

    int far = 0;
    float fx = s_pts[0], fy = s_pts[1], fz = s_pts[2];
    const int wave = t >> 6, lane = t & 63;

    for (int it = 0; it < NPOINT; ++it) {
        if (t == 0) {
            float* nx = new_xyz + ((size_t)b * NPOINT + it) * 3;
            nx[0] = fx; nx[1] = fy; nx[2] = fz;
        }
        // update min-dists, track local argmax (first-index tie-break: strict >)
        float bestv = -1.0f; int bestk = 0;
#pragma unroll
        for (int k = 0; k < 8; ++k) {
            float dx = __fsub_rn(px[k], fx);
            float dy = __fsub_rn(py[k], fy);
            float dz = __fsub_rn(pz[k], fz);
            float d  = __fadd_rn(__fadd_rn(__fmul_rn(dx, dx), __fmul_rn(dy, dy)),
                                 __fmul_rn(dz, dz));
            float nd = fminf(dist[k], d);
            dist[k] = nd;
            if (nd > bestv) { bestv = nd; bestk = k; }
        }
        int besti = t + (bestk << 10);
        // wave reduce (value desc, index asc on ties)
#pragma unroll
        for (int m = 1; m < 64; m <<= 1) {
            float ov = __shfl_xor(bestv, m, 64);
            int   oi = __shfl_xor(besti, m, 64);
            if (ov > bestv || (ov == bestv && oi < besti)) { bestv = ov; besti = oi; }
        }
        if (lane == 0) { s_val[wave] = bestv; s_idx[wave] = besti; }
        __syncthreads();
        // every thread redundantly reduces the 16 wave results (broadcast reads)
        float mv = s_val[0]; int mi = s_idx[0];
#pragma unroll
        for (int e = 1; e < 16; ++e) {
            float v = s_val[e]; int ii = s_idx[e];
            if (v > mv || (v == mv && ii < mi)) { mv = v; mi = ii; }
        }
        far = mi;
        fx = s_pts[3 * far + 0];
        fy = s_pts[3 * far + 1];
        fz = s_pts[3 * far + 2];
        __syncthreads();   // protect s_val/s_idx for next iteration
    }
}

// ---------------------------------------------------------------------------
// Kernel 2: feature transpose (B, C, N) -> (B, N, C) for coalesced gather.
// ---------------------------------------------------------------------------
__global__ __launch_bounds__(256) void transpose_kernel(const float* __restrict__ feat,
                                                        float* __restrict__ feat_t) {
    __shared__ float tile[64][65];
    const int bidx = blockIdx.x;          // b * (NPTS/64) + ntile
    const int b  = bidx >> 7;             // NPTS/64 == 128
    const int n0 = (bidx & 127) << 6;
    const int t  = threadIdx.x;
    const int i  = t & 63, c0 = t >> 6;
    const float* src = feat + (size_t)b * NCH * NPTS;
#pragma unroll
    for (int r = 0; r < 16; ++r) {
        int c = c0 + r * 4;
        tile[c][i] = src[(size_t)c * NPTS + n0 + i];
    }
    __syncthreads();
    const int cc = t & 63, i0 = t >> 6;
    float* dst = feat_t + ((size_t)b * NPTS + n0) * NCH;
#pragma unroll
    for (int r = 0; r < 16; ++r) {
        int ii = i0 + r * 4;
        dst[(size_t)ii * NCH + cc] = tile[cc][ii];
    }
}

// ---------------------------------------------------------------------------
// Kernel 3: ball query. One wave per center: scan points in 64-chunks,
// collect first NSAMPLE indices with d2 < R2 (ascending index order),
// pad with first hit (or 0).
// ---------------------------------------------------------------------------
__global__ __launch_bounds__(256) void ballquery_kernel(const float* __restrict__ xyz,
                                                        const float* __restrict__ new_xyz,
                                                        int* __restrict__ gidx) {
    const int gw   = (blockIdx.x * 256 + threadIdx.x) >> 6;  // center id
    const int lane = threadIdx.x & 63;
    const int b = gw >> 10;
    const float* nx = new_xyz + (size_t)gw * 3;
    const float cx = nx[0], cy = nx[1], cz = nx[2];
    const float* pts = xyz + (size_t)b * NPTS * 3;
    int* out = gidx + (size_t)gw * NSAMPLE;

    int cnt = 0;
    int first = 0;
    for (int j0 = 0; j0 < NPTS; j0 += 64) {
        const int j = j0 + lane;
        float x = pts[3 * j], y = pts[3 * j + 1], z = pts[3 * j + 2];
        float dx = __fsub_rn(x, cx), dy = __fsub_rn(y, cy), dz = __fsub_rn(z, cz);
        float d2 = __fadd_rn(__fadd_rn(__fmul_rn(dx, dx), __fmul_rn(dy, dy)),
                             __fmul_rn(dz, dz));
        const bool pred = d2 < R2;
        const unsigned long long mask = __ballot(pred);
        if (cnt == 0 && mask) first = j0 + (int)(__ffsll((unsigned long long)mask) - 1);
        if (pred) {
            int slot = cnt + (int)__popcll(mask & ((1ull << lane) - 1ull));
            if (slot < NSAMPLE) out[slot] = j;
        }
        cnt += (int)__popcll(mask);
        if (cnt >= NSAMPLE) break;
    }
    if (cnt < NSAMPLE) {
        if (lane >= cnt && lane < NSAMPLE) out[lane] = first;
    }
}

// ---------------------------------------------------------------------------
// Kernel 4: gather + 3-layer pointwise MLP + max-pool over samples.
// One thread per (center, sample) column; weights staged in LDS layer-by-layer.
// FMA allowed here (bf16-scale tolerance).
// ---------------------------------------------------------------------------
__global__ __launch_bounds__(256) void mlp_kernel(const float* __restrict__ xyz,
                                                  const float* __restrict__ feat_t,
                                                  const int* __restrict__ gidx,
                                                  const float* __restrict__ new_xyz,
                                                  const float* __restrict__ W1,
                                                  const float* __restrict__ b1,
                                                  const float* __restrict__ W2,
                                                  const float* __restrict__ b2,
                                                  const float* __restrict__ W3,
                                                  const float* __restrict__ b3,
                                                  float* __restrict__ out_feat) {
    __shared__ float sw[128 * 64];    // 32 KB, reused per layer
    __shared__ float sb1[64], sb2[64], sb3[128];
    const int t = threadIdx.x;

    // stage W1 padded to [64][68] (so rows are float4-aligned; col 67 = 0)
    for (int i = t; i < 64 * 67; i += 256) sw[(i / 67) * 68 + (i % 67)] = W1[i];
    if (t < 64) { sw[t * 68 + 67] = 0.0f; sb1[t] = b1[t]; sb2[t] = b2[t]; }
    if (t < 128) sb3[t] = b3[t];

    const int ci = t >> 5, s = t & 31;
    const int pg = blockIdx.x * 8 + ci;
    const int b  = pg >> 10;
    const int p  = pg & 1023;
    const int gi = gidx[(size_t)pg * NSAMPLE + s];

    const float* nx = new_xyz + (size_t)pg * 3;
    const float* pp = xyz + ((size_t)b * NPTS + gi) * 3;
    float h[68];
    h[0] = pp[0] - nx[0];
    h[1] = pp[1] - nx[1];
    h[2] = pp[2] - nx[2];
    const float4* fp = (const float4*)(feat_t + ((size_t)b * NPTS + gi) * NCH);
#pragma unroll
    for (int q = 0; q < 16; ++q) {
        float4 v = fp[q];
        h[3 + 4 * q] = v.x; h[4 + 4 * q] = v.y; h[5 + 4 * q] = v.z; h[6 + 4 * q] = v.w;
    }
    h[67] = 0.0f;
    __syncthreads();

    float h1[64];
#pragma unroll
    for (int o = 0; o < 64; ++o) {
        const float4* wr = (const float4*)(&sw[o * 68]);
        float a0 = 0.f, a1 = 0.f, a2 = 0.f, a3 = 0.f;
#pragma unroll
        for (int q = 0; q < 17; ++q) {
            float4 w = wr[q];
            a0 = fmaf(w.x, h[4 * q + 0], a0);
            a1 = fmaf(w.y, h[4 * q + 1], a1);
            a2 = fmaf(w.z, h[4 * q + 2], a2);
            a3 = fmaf(w.w, h[4 * q + 3], a3);
        }
        h1[o] = fmaxf((a0 + a1) + (a2 + a3) + sb1[o], 0.0f);
    }

    __syncthreads();
    for (int i = t; i < 64 * 64; i += 256) sw[i] = W2[i];
    __syncthreads();

    float h2[64];
#pragma unroll
    for (int o = 0; o < 64; ++o) {
        const float4* wr = (const float4*)(&sw[o * 64]);
        float a0 = 0.f, a1 = 0.f, a2 = 0.f, a3 = 0.f;
#pragma unroll
        for (int q = 0; q < 16; ++q) {
            float4 w = wr[q];
            a0 = fmaf(w.x, h1[4 * q + 0], a0);
            a1 = fmaf(w.y, h1[4 * q + 1], a1);
            a2 = fmaf(w.z, h1[4 * q + 2], a2);
            a3 = fmaf(w.w, h1[4 * q + 3], a3);
        }
        h2[o] = fmaxf((a0 + a1) + (a2 + a3) + sb2[o], 0.0f);
    }

    __syncthreads();
    for (int i = t; i < 128 * 64; i += 256) sw[i] = W3[i];
    __syncthreads();

    float* outp = out_feat + ((size_t)b * 128) * NPOINT + p;
#pragma unroll
    for (int o = 0; o < 128; ++o) {
        const float4* wr = (const float4*)(&sw[o * 64]);
        float a0 = 0.f, a1 = 0.f, a2 = 0.f, a3 = 0.f;
#pragma unroll
        for (int q = 0; q < 16; ++q) {
            float4 w = wr[q];
            a0 = fmaf(w.x, h2[4 * q + 0], a0);
            a1 = fmaf(w.y, h2[4 * q + 1], a1);
            a2 = fmaf(w.z, h2[4 * q + 2], a2);
            a3 = fmaf(w.w, h2[4 * q + 3], a3);
        }
        float acc = fmaxf((a0 + a1) + (a2 + a3) + sb3[o], 0.0f);
        // max over the 32 samples (lanes within each 32-half of the wave)
#pragma unroll
        for (int m = 1; m < 32; m <<= 1) acc = fmaxf(acc, __shfl_xor(acc, m, 64));
        if (s == 0) outp[(size_t)o * NPOINT] = acc;
    }
}

extern "C" void kernel_launch(void* const* d_in, const int* in_sizes, int n_in,
                              void* d_out, int out_size, void* d_ws, size_t ws_size,
                              hipStream_t stream) {
    const float* xyz  = (const float*)d_in[0];
    const float* feat = (const float*)d_in[1];
    const float* W1   = (const float*)d_in[2];
    const float* b1   = (const float*)d_in[3];
    const float* W2   = (const float*)d_in[4];
    const float* b2   = (const float*)d_in[5];
    const float* W3   = (const float*)d_in[6];
    const float* b3   = (const float*)d_in[7];

    float* new_xyz  = (float*)d_out;                                  // (B, NPOINT, 3)
    float* out_feat = (float*)d_out + (size_t)BATCH * NPOINT * 3;     // (B, 128, NPOINT)

    int* gidx = (int*)d_ws;                                           // (B*NPOINT, NSAMPLE)
    size_t gidx_bytes = (size_t)BATCH * NPOINT * NSAMPLE * sizeof(int);
    gidx_bytes = (gidx_bytes + 255) & ~(size_t)255;
    float* feat_t = (float*)((char*)d_ws + gidx_bytes);               // (B, NPTS, NCH)

    hipLaunchKernelGGL(transpose_kernel, dim3(BATCH * (NPTS / 64)), dim3(256), 0, stream,
                       feat, feat_t);
    hipLaunchKernelGGL(fps_kernel, dim3(BATCH), dim3(1024), 0, stream,
                       xyz, new_xyz);
    hipLaunchKernelGGL(ballquery_kernel, dim3(BATCH * NPOINT / 4), dim3(256), 0, stream,
                       xyz, new_xyz, gidx);
    hipLaunchKernelGGL(mlp_kernel, dim3(BATCH * NPOINT / 8), dim3(256), 0, stream,
                       xyz, feat_t, gidx, new_xyz,
                       W1, b1, W2, b2, W3, b3, out_feat);
}

// Round 2
// 1779.762 us; speedup vs baseline: 1.7267x; 1.7267x over previous
//
#include <hip/hip_runtime.h>

#define BATCH   16
#define NPTS    8192
#define NCH     64
#define NPOINT  1024
#define NSAMPLE 32
#define R2 0.01f

// ---------------------------------------------------------------------------
// Kernel 1 (fused): blocks 0..15 -> furthest point sampling (one block/batch);
// blocks 16..16+2047 -> feature transpose (B,C,N)->(B,N,C).
// FPS is bit-exact vs numpy: dist = ((dx*dx + dy*dy) + dz*dz) with _rn
// intrinsics (no FMA contraction), argmax with first-index tie-break.
// ---------------------------------------------------------------------------
__device__ inline unsigned long long shfl_xor_u64(unsigned long long x, int m) {
    int lo = (int)(unsigned)(x & 0xffffffffull);
    int hi = (int)(unsigned)(x >> 32);
    lo = __shfl_xor(lo, m, 64);
    hi = __shfl_xor(hi, m, 64);
    return ((unsigned long long)(unsigned)hi << 32) | (unsigned)lo;
}

__global__ __launch_bounds__(256, 1) void fps_tr_kernel(const float* __restrict__ xyz,
                                                        float* __restrict__ new_xyz,
                                                        const float* __restrict__ feat,
                                                        float* __restrict__ feat_t) {
    __shared__ float s_mem[NPTS * 3];                 // 96 KB (fps) / reused as tile (transpose)
    __shared__ unsigned long long s_red[2][4];
    const int t = threadIdx.x;

    if (blockIdx.x >= BATCH) {
        // ---------------- transpose path ----------------
        float (*tile)[65] = (float (*)[65])s_mem;
        const int bidx = blockIdx.x - BATCH;          // b * (NPTS/64) + ntile
        const int b  = bidx >> 7;
        const int n0 = (bidx & 127) << 6;
        const int i  = t & 63, c0 = t >> 6;
        const float* src = feat + (size_t)b * NCH * NPTS;
#pragma unroll
        for (int r = 0; r < 16; ++r) {
            int c = c0 + r * 4;
            tile[c][i] = src[(size_t)c * NPTS + n0 + i];
        }
        __syncthreads();
        const int cc = t & 63, i0 = t >> 6;
        float* dst = feat_t + ((size_t)b * NPTS + n0) * NCH;
#pragma unroll
        for (int r = 0; r < 16; ++r) {
            int ii = i0 + r * 4;
            dst[(size_t)ii * NCH + cc] = tile[cc][ii];
        }
        return;
    }

    // ---------------- FPS path ----------------
    const int b = blockIdx.x;
    const float* g = xyz + (size_t)b * NPTS * 3;
    for (int i = t; i < NPTS * 3; i += 256) s_mem[i] = g[i];
    __syncthreads();

    float px[32], py[32], pz[32], dist[32];
#pragma unroll
    for (int k = 0; k < 32; ++k) {
        const int p = t + (k << 8);
        px[k] = s_mem[3 * p + 0];
        py[k] = s_mem[3 * p + 1];
        pz[k] = s_mem[3 * p + 2];
        dist[k] = 1e10f;
    }

    float fx = s_mem[0], fy = s_mem[1], fz = s_mem[2];
    const int wave = t >> 6;

    for (int it = 0; it < NPOINT; ++it) {
        if (t == 0) {
            float* nx = new_xyz + ((size_t)b * NPOINT + it) * 3;
            nx[0] = fx; nx[1] = fy; nx[2] = fz;
        }
        // update min-dists, track lane-local argmax (first-index tie-break)
        float bestv = -1.0f; int bestk = 0;
#pragma unroll
        for (int k = 0; k < 32; ++k) {
            float dx = __fsub_rn(px[k], fx);
            float dy = __fsub_rn(py[k], fy);
            float dz = __fsub_rn(pz[k], fz);
            float d  = __fadd_rn(__fadd_rn(__fmul_rn(dx, dx), __fmul_rn(dy, dy)),
                                 __fmul_rn(dz, dz));
            float nd = fminf(dist[k], d);
            dist[k] = nd;
            if (nd > bestv) { bestv = nd; bestk = k; }   // ascending k => first index wins
        }
        const int besti = t + (bestk << 8);
        // key: max value, then min index (dist >= 0 so float bits are monotonic)
        unsigned long long key =
            ((unsigned long long)__float_as_uint(bestv) << 32) | (unsigned)(~besti);
#pragma unroll
        for (int m = 1; m < 64; m <<= 1) {
            unsigned long long o = shfl_xor_u64(key, m);
            if (o > key) key = o;
        }
        const int par = it & 1;
        if ((t & 63) == 0) s_red[par][wave] = key;
        __syncthreads();
        unsigned long long kk = s_red[par][0];
        unsigned long long k1 = s_red[par][1];
        unsigned long long k2 = s_red[par][2];
        unsigned long long k3 = s_red[par][3];
        if (k1 > kk) kk = k1;
        if (k2 > kk) kk = k2;
        if (k3 > kk) kk = k3;
        const int far = (int)(~(unsigned)kk);
        fx = s_mem[3 * far + 0];
        fy = s_mem[3 * far + 1];
        fz = s_mem[3 * far + 2];
    }
}

// ---------------------------------------------------------------------------
// Kernel 2: ball query. One wave per center.
// ---------------------------------------------------------------------------
__global__ __launch_bounds__(256) void ballquery_kernel(const float* __restrict__ xyz,
                                                        const float* __restrict__ new_xyz,
                                                        int* __restrict__ gidx) {
    const int gw   = (blockIdx.x * 256 + threadIdx.x) >> 6;  // center id
    const int lane = threadIdx.x & 63;
    const int b = gw >> 10;
    const float* nx = new_xyz + (size_t)gw * 3;
    const float cx = nx[0], cy = nx[1], cz = nx[2];
    const float* pts = xyz + (size_t)b * NPTS * 3;
    int* out = gidx + (size_t)gw * NSAMPLE;

    int cnt = 0;
    int first = 0;
    for (int j0 = 0; j0 < NPTS; j0 += 64) {
        const int j = j0 + lane;
        float x = pts[3 * j], y = pts[3 * j + 1], z = pts[3 * j + 2];
        float dx = __fsub_rn(x, cx), dy = __fsub_rn(y, cy), dz = __fsub_rn(z, cz);
        float d2 = __fadd_rn(__fadd_rn(__fmul_rn(dx, dx), __fmul_rn(dy, dy)),
                             __fmul_rn(dz, dz));
        const bool pred = d2 < R2;
        const unsigned long long mask = __ballot(pred);
        if (cnt == 0 && mask) first = j0 + (int)(__ffsll((unsigned long long)mask) - 1);
        if (pred) {
            int slot = cnt + (int)__popcll(mask & ((1ull << lane) - 1ull));
            if (slot < NSAMPLE) out[slot] = j;
        }
        cnt += (int)__popcll(mask);
        if (cnt >= NSAMPLE) break;
    }
    if (cnt < NSAMPLE) {
        if (lane >= cnt && lane < NSAMPLE) out[lane] = first;
    }
}

// ---------------------------------------------------------------------------
// Kernel 3: gather + 3-layer pointwise MLP + max-pool over samples.
// ---------------------------------------------------------------------------
__global__ __launch_bounds__(256) void mlp_kernel(const float* __restrict__ xyz,
                                                  const float* __restrict__ feat_t,
                                                  const int* __restrict__ gidx,
                                                  const float* __restrict__ new_xyz,
                                                  const float* __restrict__ W1,
                                                  const float* __restrict__ b1,
                                                  const float* __restrict__ W2,
                                                  const float* __restrict__ b2,
                                                  const float* __restrict__ W3,
                                                  const float* __restrict__ b3,
                                                  float* __restrict__ out_feat) {
    __shared__ float sw[128 * 64];    // 32 KB, reused per layer
    __shared__ float sb1[64], sb2[64], sb3[128];
    const int t = threadIdx.x;

    for (int i = t; i < 64 * 67; i += 256) sw[(i / 67) * 68 + (i % 67)] = W1[i];
    if (t < 64) { sw[t * 68 + 67] = 0.0f; sb1[t] = b1[t]; sb2[t] = b2[t]; }
    if (t < 128) sb3[t] = b3[t];

    const int ci = t >> 5, s = t & 31;
    const int pg = blockIdx.x * 8 + ci;
    const int b  = pg >> 10;
    const int p  = pg & 1023;
    const int gi = gidx[(size_t)pg * NSAMPLE + s];

    const float* nx = new_xyz + (size_t)pg * 3;
    const float* pp = xyz + ((size_t)b * NPTS + gi) * 3;
    float h[68];
    h[0] = pp[0] - nx[0];
    h[1] = pp[1] - nx[1];
    h[2] = pp[2] - nx[2];
    const float4* fp = (const float4*)(feat_t + ((size_t)b * NPTS + gi) * NCH);
#pragma unroll
    for (int q = 0; q < 16; ++q) {
        float4 v = fp[q];
        h[3 + 4 * q] = v.x; h[4 + 4 * q] = v.y; h[5 + 4 * q] = v.z; h[6 + 4 * q] = v.w;
    }
    h[67] = 0.0f;
    __syncthreads();

    float h1[64];
#pragma unroll
    for (int o = 0; o < 64; ++o) {
        const float4* wr = (const float4*)(&sw[o * 68]);
        float a0 = 0.f, a1 = 0.f, a2 = 0.f, a3 = 0.f;
#pragma unroll
        for (int q = 0; q < 17; ++q) {
            float4 w = wr[q];
            a0 = fmaf(w.x, h[4 * q + 0], a0);
            a1 = fmaf(w.y, h[4 * q + 1], a1);
            a2 = fmaf(w.z, h[4 * q + 2], a2);
            a3 = fmaf(w.w, h[4 * q + 3], a3);
        }
        h1[o] = fmaxf((a0 + a1) + (a2 + a3) + sb1[o], 0.0f);
    }

    __syncthreads();
    for (int i = t; i < 64 * 64; i += 256) sw[i] = W2[i];
    __syncthreads();

    float h2[64];
#pragma unroll
    for (int o = 0; o < 64; ++o) {
        const float4* wr = (const float4*)(&sw[o * 64]);
        float a0 = 0.f, a1 = 0.f, a2 = 0.f, a3 = 0.f;
#pragma unroll
        for (int q = 0; q < 16; ++q) {
            float4 w = wr[q];
            a0 = fmaf(w.x, h1[4 * q + 0], a0);
            a1 = fmaf(w.y, h1[4 * q + 1], a1);
            a2 = fmaf(w.z, h1[4 * q + 2], a2);
            a3 = fmaf(w.w, h1[4 * q + 3], a3);
        }
        h2[o] = fmaxf((a0 + a1) + (a2 + a3) + sb2[o], 0.0f);
    }

    __syncthreads();
    for (int i = t; i < 128 * 64; i += 256) sw[i] = W3[i];
    __syncthreads();

    float* outp = out_feat + ((size_t)b * 128) * NPOINT + p;
#pragma unroll
    for (int o = 0; o < 128; ++o) {
        const float4* wr = (const float4*)(&sw[o * 64]);
        float a0 = 0.f, a1 = 0.f, a2 = 0.f, a3 = 0.f;
#pragma unroll
        for (int q = 0; q < 16; ++q) {
            float4 w = wr[q];
            a0 = fmaf(w.x, h2[4 * q + 0], a0);
            a1 = fmaf(w.y, h2[4 * q + 1], a1);
            a2 = fmaf(w.z, h2[4 * q + 2], a2);
            a3 = fmaf(w.w, h2[4 * q + 3], a3);
        }
        float acc = fmaxf((a0 + a1) + (a2 + a3) + sb3[o], 0.0f);
#pragma unroll
        for (int m = 1; m < 32; m <<= 1) acc = fmaxf(acc, __shfl_xor(acc, m, 64));
        if (s == 0) outp[(size_t)o * NPOINT] = acc;
    }
}

extern "C" void kernel_launch(void* const* d_in, const int* in_sizes, int n_in,
                              void* d_out, int out_size, void* d_ws, size_t ws_size,
                              hipStream_t stream) {
    const float* xyz  = (const float*)d_in[0];
    const float* feat = (const float*)d_in[1];
    const float* W1   = (const float*)d_in[2];
    const float* b1   = (const float*)d_in[3];
    const float* W2   = (const float*)d_in[4];
    const float* b2   = (const float*)d_in[5];
    const float* W3   = (const float*)d_in[6];
    const float* b3   = (const float*)d_in[7];

    float* new_xyz  = (float*)d_out;                                  // (B, NPOINT, 3)
    float* out_feat = (float*)d_out + (size_t)BATCH * NPOINT * 3;     // (B, 128, NPOINT)

    int* gidx = (int*)d_ws;                                           // (B*NPOINT, NSAMPLE)
    size_t gidx_bytes = (size_t)BATCH * NPOINT * NSAMPLE * sizeof(int);
    gidx_bytes = (gidx_bytes + 255) & ~(size_t)255;
    float* feat_t = (float*)((char*)d_ws + gidx_bytes);               // (B, NPTS, NCH)

    hipLaunchKernelGGL(fps_tr_kernel, dim3(BATCH + BATCH * (NPTS / 64)), dim3(256), 0, stream,
                       xyz, new_xyz, feat, feat_t);
    hipLaunchKernelGGL(ballquery_kernel, dim3(BATCH * NPOINT / 4), dim3(256), 0, stream,
                       xyz, new_xyz, gidx);
    hipLaunchKernelGGL(mlp_kernel, dim3(BATCH * NPOINT / 8), dim3(256), 0, stream,
                       xyz, feat_t, gidx, new_xyz,
                       W1, b1, W2, b2, W3, b3, out_feat);
}